// Round 1
// baseline (1321.259 us; speedup 1.0000x reference)
//
#include <hip/hip_runtime.h>
#include <stdint.h>

// Problem constants
#define B_    8
#define T_    4096
#define HID   512
#define SD    256
#define NH    8
#define HD    32
#define M_TOK (B_*T_)          // 32768 tokens
#define NPROJ 1536             // 6 * 256 output channels (k,v,q,beta,alpha,gate)

typedef __attribute__((ext_vector_type(8))) short short8;   // 8 bf16 (4 VGPRs) — MFMA A/B frag
typedef __attribute__((ext_vector_type(4))) float f32x4;    // MFMA C/D frag

__device__ __forceinline__ unsigned short f2bf(float f) {
  // round-to-nearest-even f32 -> bf16 (bit-level)
  uint32_t u = __float_as_uint(f);
  uint32_t r = (u + 0x7fffu + ((u >> 16) & 1u)) >> 16;
  return (unsigned short)r;
}

__device__ __forceinline__ void gload16(const void* g, void* l) {
  // async global->LDS, 16B per lane; LDS dest = wave-uniform base + lane*16
  __builtin_amdgcn_global_load_lds((const __attribute__((address_space(1))) void*)g,
                                   (__attribute__((address_space(3))) void*)l,
                                   16, 0, 0);
}

// ---------------------------------------------------------------- converts
__global__ void cvt_f32_bf16(const float* __restrict__ in, unsigned short* __restrict__ out, int n4) {
  int i = blockIdx.x * blockDim.x + threadIdx.x;
  int stride = gridDim.x * blockDim.x;
  for (; i < n4; i += stride) {
    float4 v = reinterpret_cast<const float4*>(in)[i];
    ushort4 o;
    o.x = f2bf(v.x); o.y = f2bf(v.y); o.z = f2bf(v.z); o.w = f2bf(v.w);
    reinterpret_cast<ushort4*>(out)[i] = o;
  }
}

// ---------------------------------------------------------------- projection GEMM
// C[m, n] = hb[m, :] . Wc[n, :]   (m: 32768 tokens, n: 1536 channels, K=512)
// BM=128, BN=64, BK=64; 256 threads = 4 waves; wave w -> rows [w*32, w*32+32), all 64 cols.
// LDS tiles row-major [row][k] with per-row XOR swizzle of 16B segments (seg ^= row&7),
// achieved by pre-swizzling the GLOBAL source (LDS dest of global_load_lds must stay linear).
#define PM 128
#define PN 64
#define PK 64

__global__ void __launch_bounds__(256) proj_gemm(
    const unsigned short* __restrict__ hb, const unsigned short* __restrict__ Wc,
    const float* __restrict__ b_beta, const float* __restrict__ b_alpha,
    float* __restrict__ Kp, float* __restrict__ Vp, float* __restrict__ Qp,
    float* __restrict__ Bp, float* __restrict__ Ap, float* __restrict__ gate)
{
  __shared__ unsigned short Asm[PM*PK];  // 16 KB
  __shared__ unsigned short Bsm[PN*PK];  // 8 KB
  const int t = threadIdx.x;
  const int w = t >> 6, lane = t & 63;
  const int bm0 = blockIdx.x * PM;
  const int bn0 = blockIdx.y * PN;

  f32x4 acc[2][4];
  #pragma unroll
  for (int i = 0; i < 2; ++i)
    #pragma unroll
    for (int j = 0; j < 4; ++j) acc[i][j] = (f32x4){0.f, 0.f, 0.f, 0.f};

  for (int k0 = 0; k0 < HID; k0 += PK) {
    // stage A: 1024 x 16B units; unit = t + it*256 -> lds byte unit*16
    #pragma unroll
    for (int it = 0; it < 4; ++it) {
      int unit = t + it * 256;
      int row = unit >> 3, seg = unit & 7;
      int dseg = seg ^ (row & 7);
      const unsigned short* g = hb + (size_t)(bm0 + row) * HID + k0 + dseg * 8;
      gload16(g, (char*)Asm + (w * 1024 + it * 4096));
    }
    // stage B: 512 x 16B units
    #pragma unroll
    for (int it = 0; it < 2; ++it) {
      int unit = t + it * 256;
      int n = unit >> 3, seg = unit & 7;
      int dseg = seg ^ (n & 7);
      const unsigned short* g = Wc + (size_t)(bn0 + n) * HID + k0 + dseg * 8;
      gload16(g, (char*)Bsm + (w * 1024 + it * 4096));
    }
    __syncthreads();   // drains vmcnt(0) before barrier
    #pragma unroll
    for (int ks = 0; ks < 2; ++ks) {
      short8 af[2], bfr[4];
      int u = ks * 4 + (lane >> 4);
      int slot = u ^ (lane & 7);
      #pragma unroll
      for (int rb = 0; rb < 2; ++rb) {
        int row = w * 32 + rb * 16 + (lane & 15);
        af[rb] = *(const short8*)((const char*)Asm + row * 128 + slot * 16);
      }
      #pragma unroll
      for (int cb = 0; cb < 4; ++cb) {
        int nn = cb * 16 + (lane & 15);
        bfr[cb] = *(const short8*)((const char*)Bsm + nn * 128 + slot * 16);
      }
      #pragma unroll
      for (int rb = 0; rb < 2; ++rb)
        #pragma unroll
        for (int cb = 0; cb < 4; ++cb)
          acc[rb][cb] = __builtin_amdgcn_mfma_f32_16x16x32_bf16(af[rb], bfr[cb], acc[rb][cb], 0, 0, 0);
    }
    __syncthreads();
  }

  // epilogue: p region is uniform per block (BN=64, regions are 256-aligned)
  const int p = bn0 >> 8;   // 0:k 1:v 2:q 3:beta 4:alpha 5:gate
  float* outp = (p == 0) ? Kp : (p == 1) ? Vp : (p == 2) ? Qp : (p == 3) ? Bp : (p == 4) ? Ap : gate;
  #pragma unroll
  for (int rb = 0; rb < 2; ++rb) {
    #pragma unroll
    for (int cb = 0; cb < 4; ++cb) {
      int n = bn0 + cb * 16 + (lane & 15);
      int rem = n & 255;
      #pragma unroll
      for (int r = 0; r < 4; ++r) {
        int m = bm0 + w * 32 + rb * 16 + (lane >> 4) * 4 + r;
        float v = acc[rb][cb][r];
        if (p == 3) v = 1.0f / (1.0f + expf(-(v + b_beta[rem])));
        else if (p == 4) v = 1.0f / (1.0f + expf(-(v + b_alpha[rem])));
        if (p == 5) {
          gate[(size_t)m * SD + rem] = v;
        } else {
          int b = m >> 12, tt = m & 4095;
          int h = rem >> 5, d = rem & 31;
          outp[((size_t)(b * NH + h) * T_ + tt) * HD + d] = v;
        }
      }
    }
  }
}

// ---------------------------------------------------------------- k normalization
// Kp laid out [b*8+h][t][32]; one 32-lane group per row.
__global__ void __launch_bounds__(256) knorm(float* __restrict__ Kp) {
  int t = threadIdx.x;
  size_t row = (size_t)blockIdx.x * 8 + (t >> 5);
  int j = t & 31;
  float x = Kp[row * 32 + j];
  float s = x * x;
  #pragma unroll
  for (int m = 16; m >= 1; m >>= 1) s += __shfl_xor(s, m, 32);
  float inv = 1.0f / fmaxf(sqrtf(s), 1e-12f);
  Kp[row * 32 + j] = x * inv;
}

// ---------------------------------------------------------------- sequential scan
// One block per (b,h). 128 threads = 2 waves. Rows of S are independent:
// wave wv owns rows wv*16..wv*16+15; each row split across 4 lanes (part = lane>>4),
// 8 state columns per lane. Dots reduce via shfl_xor(16) + shfl_xor(32).
// Inputs double-buffered in LDS via global_load_lds, chunk = 32 steps.
#define CH 32
__global__ void __launch_bounds__(128) scan_kernel(
    const float* __restrict__ Kp, const float* __restrict__ Vp,
    const float* __restrict__ Qp, const float* __restrict__ Bp,
    const float* __restrict__ Ap, const float* __restrict__ state_in,
    float* __restrict__ ctx, float* __restrict__ Sfin)
{
  __shared__ float Kc[2][CH*32], Qc[2][CH*32], Vc[2][CH*32], Ac[2][CH*32], Bc[2][CH*32]; // 40 KB
  const int bh = blockIdx.x;
  const int b = bh >> 3, h = bh & 7;
  const int t = threadIdx.x;
  const int wv = t >> 6, lane = t & 63;
  const int i = wv * 16 + (lane & 15);   // state row 0..31
  const int part = lane >> 4;            // 0..3 (8 cols each)
  const size_t base = (size_t)bh * (T_ * HD);

  float S[8];
  #pragma unroll
  for (int c = 0; c < 8; ++c) S[c] = state_in[(size_t)bh * 1024 + i * 32 + part * 8 + c];

  auto stage = [&](int ci, int buf) {
    #pragma unroll
    for (int it = 0; it < 2; ++it) {
      size_t goff = base + (size_t)ci * (CH * 32) + (size_t)(t + it * 128) * 4;
      int lb = wv * 1024 + it * 2048;   // uniform byte base; HW adds lane*16
      gload16(Kp + goff, (char*)&Kc[buf][0] + lb);
      gload16(Qp + goff, (char*)&Qc[buf][0] + lb);
      gload16(Vp + goff, (char*)&Vc[buf][0] + lb);
      gload16(Ap + goff, (char*)&Ac[buf][0] + lb);
      gload16(Bp + goff, (char*)&Bc[buf][0] + lb);
    }
  };

  stage(0, 0);
  __syncthreads();
  const int NCH = T_ / CH;  // 128
  for (int ci = 0; ci < NCH; ++ci) {
    int buf = ci & 1;
    if (ci + 1 < NCH) stage(ci + 1, buf ^ 1);
    #pragma unroll 2
    for (int tc = 0; tc < CH; ++tc) {
      int tg = ci * CH + tc;
      const float4 k0 = *(const float4*)&Kc[buf][tc * 32 + part * 8];
      const float4 k1 = *(const float4*)&Kc[buf][tc * 32 + part * 8 + 4];
      const float4 q0 = *(const float4*)&Qc[buf][tc * 32 + part * 8];
      const float4 q1 = *(const float4*)&Qc[buf][tc * 32 + part * 8 + 4];
      float a  = Ac[buf][tc * 32 + i];
      float vv = Vc[buf][tc * 32 + i];
      float be = Bc[buf][tc * 32 + i];

      float pa = S[0] * k0.x, pb = S[1] * k0.y;
      pa = fmaf(S[2], k0.z, pa); pb = fmaf(S[3], k0.w, pb);
      pa = fmaf(S[4], k1.x, pa); pb = fmaf(S[5], k1.y, pb);
      pa = fmaf(S[6], k1.z, pa); pb = fmaf(S[7], k1.w, pb);
      float pr = pa + pb;
      pr += __shfl_xor(pr, 16, 64);
      pr += __shfl_xor(pr, 32, 64);
      pr *= a;                          // pred_i = a_i * (S k̂)
      float u = be * (vv - pr);

      S[0] = fmaf(u, k0.x, a * S[0]);
      S[1] = fmaf(u, k0.y, a * S[1]);
      S[2] = fmaf(u, k0.z, a * S[2]);
      S[3] = fmaf(u, k0.w, a * S[3]);
      S[4] = fmaf(u, k1.x, a * S[4]);
      S[5] = fmaf(u, k1.y, a * S[5]);
      S[6] = fmaf(u, k1.z, a * S[6]);
      S[7] = fmaf(u, k1.w, a * S[7]);

      float oa = S[0] * q0.x, ob = S[1] * q0.y;
      oa = fmaf(S[2], q0.z, oa); ob = fmaf(S[3], q0.w, ob);
      oa = fmaf(S[4], q1.x, oa); ob = fmaf(S[5], q1.y, ob);
      oa = fmaf(S[6], q1.z, oa); ob = fmaf(S[7], q1.w, ob);
      float o = oa + ob;
      o += __shfl_xor(o, 16, 64);
      o += __shfl_xor(o, 32, 64);
      if (part == 0) ctx[((size_t)(b * T_ + tg)) * SD + h * HD + i] = o;
    }
    __syncthreads();  // drains vmcnt -> next chunk staged, and buf reads done
  }
  #pragma unroll
  for (int c = 0; c < 8; ++c) Sfin[(size_t)bh * 1024 + i * 32 + part * 8 + c] = S[c];
}

// ---------------------------------------------------------------- rmsnorm * silu(gate) -> bf16
__global__ void __launch_bounds__(256) rms_silu(
    const float* __restrict__ ctx, const float* __restrict__ gate,
    const float* __restrict__ norm_w, unsigned short* __restrict__ ctx2)
{
  size_t row = (size_t)blockIdx.x * 4 + (threadIdx.x >> 6);
  int lane = threadIdx.x & 63;
  const float4 x = *(const float4*)&ctx[row * SD + lane * 4];
  float s = x.x * x.x + x.y * x.y + x.z * x.z + x.w * x.w;
  #pragma unroll
  for (int m = 32; m >= 1; m >>= 1) s += __shfl_xor(s, m, 64);
  float rs = 1.0f / sqrtf(s * (1.0f / 256.0f) + 1e-6f);
  const float4 g = *(const float4*)&gate[row * SD + lane * 4];
  const float4 w = *(const float4*)&norm_w[lane * 4];
  ushort4 o;
  o.x = f2bf(x.x * rs * w.x * (g.x / (1.0f + expf(-g.x))));
  o.y = f2bf(x.y * rs * w.y * (g.y / (1.0f + expf(-g.y))));
  o.z = f2bf(x.z * rs * w.z * (g.z / (1.0f + expf(-g.z))));
  o.w = f2bf(x.w * rs * w.w * (g.w / (1.0f + expf(-g.w))));
  *(ushort4*)&ctx2[row * SD + lane * 4] = o;
}

// ---------------------------------------------------------------- output GEMM
// out[m, n] = ctx2[m, :] . Wob[n, :]   (K=256, N=512), fp32 out.
__global__ void __launch_bounds__(256) out_gemm(
    const unsigned short* __restrict__ ctx2, const unsigned short* __restrict__ Wob,
    float* __restrict__ out)
{
  __shared__ unsigned short Asm[PM*PK];
  __shared__ unsigned short Bsm[PN*PK];
  const int t = threadIdx.x;
  const int w = t >> 6, lane = t & 63;
  const int bm0 = blockIdx.x * PM;
  const int bn0 = blockIdx.y * PN;

  f32x4 acc[2][4];
  #pragma unroll
  for (int i = 0; i < 2; ++i)
    #pragma unroll
    for (int j = 0; j < 4; ++j) acc[i][j] = (f32x4){0.f, 0.f, 0.f, 0.f};

  for (int k0 = 0; k0 < SD; k0 += PK) {
    #pragma unroll
    for (int it = 0; it < 4; ++it) {
      int unit = t + it * 256;
      int row = unit >> 3, seg = unit & 7;
      int dseg = seg ^ (row & 7);
      const unsigned short* g = ctx2 + (size_t)(bm0 + row) * SD + k0 + dseg * 8;
      gload16(g, (char*)Asm + (w * 1024 + it * 4096));
    }
    #pragma unroll
    for (int it = 0; it < 2; ++it) {
      int unit = t + it * 256;
      int n = unit >> 3, seg = unit & 7;
      int dseg = seg ^ (n & 7);
      const unsigned short* g = Wob + (size_t)(bn0 + n) * SD + k0 + dseg * 8;
      gload16(g, (char*)Bsm + (w * 1024 + it * 4096));
    }
    __syncthreads();
    #pragma unroll
    for (int ks = 0; ks < 2; ++ks) {
      short8 af[2], bfr[4];
      int u = ks * 4 + (lane >> 4);
      int slot = u ^ (lane & 7);
      #pragma unroll
      for (int rb = 0; rb < 2; ++rb) {
        int row = w * 32 + rb * 16 + (lane & 15);
        af[rb] = *(const short8*)((const char*)Asm + row * 128 + slot * 16);
      }
      #pragma unroll
      for (int cb = 0; cb < 4; ++cb) {
        int nn = cb * 16 + (lane & 15);
        bfr[cb] = *(const short8*)((const char*)Bsm + nn * 128 + slot * 16);
      }
      #pragma unroll
      for (int rb = 0; rb < 2; ++rb)
        #pragma unroll
        for (int cb = 0; cb < 4; ++cb)
          acc[rb][cb] = __builtin_amdgcn_mfma_f32_16x16x32_bf16(af[rb], bfr[cb], acc[rb][cb], 0, 0, 0);
    }
    __syncthreads();
  }
  #pragma unroll
  for (int rb = 0; rb < 2; ++rb)
    #pragma unroll
    for (int cb = 0; cb < 4; ++cb) {
      int n = bn0 + cb * 16 + (lane & 15);
      #pragma unroll
      for (int r = 0; r < 4; ++r) {
        int m = bm0 + w * 32 + rb * 16 + (lane >> 4) * 4 + r;
        out[(size_t)m * 512 + n] = acc[rb][cb][r];
      }
    }
}

// ---------------------------------------------------------------- launcher
// ws layout (bytes):
//   hb   bf16 [32768][512]        @ 0          (33,554,432)
//   Wc   bf16 [1536][512]         @ 33554432   (1,572,864)   rows: k,v,q,beta,alpha,gate
//   Wob  bf16 [512][256]          @ 35127296   (262,144)
//   Kp/Vp/Qp/Bp/Ap f32 [64][4096][32] @ 35389440, 5 x 33,554,432
//   gate f32 [32768][256]         @ 203161600  (33,554,432)
//   ctx2 bf16 [32768][256]        @ 236716032  (16,777,216)
// total ~253.5 MB. fp32 ctx lives in d_out[0..8388608) (overwritten by out_gemm).
extern "C" void kernel_launch(void* const* d_in, const int* in_sizes, int n_in,
                              void* d_out, int out_size, void* d_ws, size_t ws_size,
                              hipStream_t stream) {
  (void)in_sizes; (void)n_in; (void)out_size; (void)ws_size;
  const float* hidden  = (const float*)d_in[0];
  const float* state   = (const float*)d_in[1];
  const float* W_k     = (const float*)d_in[2];
  const float* W_v     = (const float*)d_in[3];
  const float* W_q     = (const float*)d_in[4];
  const float* W_beta  = (const float*)d_in[5];
  const float* b_beta  = (const float*)d_in[6];
  const float* W_alpha = (const float*)d_in[7];
  const float* b_alpha = (const float*)d_in[8];
  const float* W_out   = (const float*)d_in[9];
  const float* gate_W  = (const float*)d_in[10];
  const float* norm_w  = (const float*)d_in[11];
  float* out = (float*)d_out;

  char* ws = (char*)d_ws;
  unsigned short* hb  = (unsigned short*)(ws);
  unsigned short* Wc  = (unsigned short*)(ws + 33554432);
  unsigned short* Wob = (unsigned short*)(ws + 35127296);
  float* Kp   = (float*)(ws + 35389440);
  float* Vp   = Kp + 8388608;
  float* Qp   = Vp + 8388608;
  float* Bp   = Qp + 8388608;
  float* Ap   = Bp + 8388608;
  float* gate = Ap + 8388608;
  unsigned short* ctx2 = (unsigned short*)(ws + 236716032);
  float* ctx  = out;                 // fp32 scratch, overwritten by out_gemm
  float* Sfin = out + 16777216;      // final state output

  cvt_f32_bf16<<<2048, 256, 0, stream>>>(hidden, hb, M_TOK * HID / 4);
  cvt_f32_bf16<<<64, 256, 0, stream>>>(W_k,     Wc + 0 * 131072, 32768);
  cvt_f32_bf16<<<64, 256, 0, stream>>>(W_v,     Wc + 1 * 131072, 32768);
  cvt_f32_bf16<<<64, 256, 0, stream>>>(W_q,     Wc + 2 * 131072, 32768);
  cvt_f32_bf16<<<64, 256, 0, stream>>>(W_beta,  Wc + 3 * 131072, 32768);
  cvt_f32_bf16<<<64, 256, 0, stream>>>(W_alpha, Wc + 4 * 131072, 32768);
  cvt_f32_bf16<<<64, 256, 0, stream>>>(gate_W,  Wc + 5 * 131072, 32768);
  cvt_f32_bf16<<<64, 256, 0, stream>>>(W_out,   Wob, 32768);

  proj_gemm<<<dim3(256, 24), 256, 0, stream>>>(hb, Wc, b_beta, b_alpha, Kp, Vp, Qp, Bp, Ap, gate);
  knorm<<<32768, 256, 0, stream>>>(Kp);
  scan_kernel<<<64, 128, 0, stream>>>(Kp, Vp, Qp, Bp, Ap, state, ctx, Sfin);
  rms_silu<<<8192, 256, 0, stream>>>(ctx, gate, norm_w, ctx2);
  out_gemm<<<dim3(256, 8), 256, 0, stream>>>(ctx2, Wob, out);
}

// Round 2
// 858.603 us; speedup vs baseline: 1.5388x; 1.5388x over previous
//
#include <hip/hip_runtime.h>
#include <stdint.h>

// Problem constants
#define B_    8
#define T_    4096
#define HID   512
#define SD    256
#define NH    8
#define HD    32
#define M_TOK (B_*T_)          // 32768 tokens
#define NPROJ 1536             // 6 * 256 output channels (k,v,q,beta,alpha,gate)

typedef __attribute__((ext_vector_type(8))) short short8;   // 8 bf16 (4 VGPRs) — MFMA A/B frag
typedef __attribute__((ext_vector_type(4))) float f32x4;    // MFMA C/D frag

__device__ __forceinline__ unsigned short f2bf(float f) {
  uint32_t u = __float_as_uint(f);
  uint32_t r = (u + 0x7fffu + ((u >> 16) & 1u)) >> 16;
  return (unsigned short)r;
}

__device__ __forceinline__ void gload16(const void* g, void* l) {
  // async global->LDS, 16B per lane; LDS dest = wave-uniform base + lane*16
  __builtin_amdgcn_global_load_lds((const __attribute__((address_space(1))) void*)g,
                                   (__attribute__((address_space(3))) void*)l,
                                   16, 0, 0);
}

// butterfly sum across the 4 lanes of a quad — pure VALU (DPP), no DS pipe
__device__ __forceinline__ float qred(float x) {
  x += __int_as_float(__builtin_amdgcn_mov_dpp(__float_as_int(x), 0xB1, 0xF, 0xF, true)); // lane^1
  x += __int_as_float(__builtin_amdgcn_mov_dpp(__float_as_int(x), 0x4E, 0xF, 0xF, true)); // lane^2
  return x;
}

// ---------------------------------------------------------------- converts
__global__ void cvt_f32_bf16(const float* __restrict__ in, unsigned short* __restrict__ out, int n4) {
  int i = blockIdx.x * blockDim.x + threadIdx.x;
  int stride = gridDim.x * blockDim.x;
  for (; i < n4; i += stride) {
    float4 v = reinterpret_cast<const float4*>(in)[i];
    ushort4 o;
    o.x = f2bf(v.x); o.y = f2bf(v.y); o.z = f2bf(v.z); o.w = f2bf(v.w);
    reinterpret_cast<ushort4*>(out)[i] = o;
  }
}

// ---------------------------------------------------------------- projection GEMM
#define PM 128
#define PN 64
#define PK 64

__global__ void __launch_bounds__(256) proj_gemm(
    const unsigned short* __restrict__ hb, const unsigned short* __restrict__ Wc,
    const float* __restrict__ b_beta, const float* __restrict__ b_alpha,
    float* __restrict__ Kp, float* __restrict__ Vp, float* __restrict__ Qp,
    float* __restrict__ Bp, float* __restrict__ Ap, float* __restrict__ gate)
{
  __shared__ unsigned short Asm[PM*PK];  // 16 KB
  __shared__ unsigned short Bsm[PN*PK];  // 8 KB
  const int t = threadIdx.x;
  const int w = t >> 6, lane = t & 63;
  const int bm0 = blockIdx.x * PM;
  const int bn0 = blockIdx.y * PN;

  f32x4 acc[2][4];
  #pragma unroll
  for (int i = 0; i < 2; ++i)
    #pragma unroll
    for (int j = 0; j < 4; ++j) acc[i][j] = (f32x4){0.f, 0.f, 0.f, 0.f};

  for (int k0 = 0; k0 < HID; k0 += PK) {
    #pragma unroll
    for (int it = 0; it < 4; ++it) {
      int unit = t + it * 256;
      int row = unit >> 3, seg = unit & 7;
      int dseg = seg ^ (row & 7);
      const unsigned short* g = hb + (size_t)(bm0 + row) * HID + k0 + dseg * 8;
      gload16(g, (char*)Asm + (w * 1024 + it * 4096));
    }
    #pragma unroll
    for (int it = 0; it < 2; ++it) {
      int unit = t + it * 256;
      int n = unit >> 3, seg = unit & 7;
      int dseg = seg ^ (n & 7);
      const unsigned short* g = Wc + (size_t)(bn0 + n) * HID + k0 + dseg * 8;
      gload16(g, (char*)Bsm + (w * 1024 + it * 4096));
    }
    __syncthreads();
    #pragma unroll
    for (int ks = 0; ks < 2; ++ks) {
      short8 af[2], bfr[4];
      int u = ks * 4 + (lane >> 4);
      int slot = u ^ (lane & 7);
      #pragma unroll
      for (int rb = 0; rb < 2; ++rb) {
        int row = w * 32 + rb * 16 + (lane & 15);
        af[rb] = *(const short8*)((const char*)Asm + row * 128 + slot * 16);
      }
      #pragma unroll
      for (int cb = 0; cb < 4; ++cb) {
        int nn = cb * 16 + (lane & 15);
        bfr[cb] = *(const short8*)((const char*)Bsm + nn * 128 + slot * 16);
      }
      #pragma unroll
      for (int rb = 0; rb < 2; ++rb)
        #pragma unroll
        for (int cb = 0; cb < 4; ++cb)
          acc[rb][cb] = __builtin_amdgcn_mfma_f32_16x16x32_bf16(af[rb], bfr[cb], acc[rb][cb], 0, 0, 0);
    }
    __syncthreads();
  }

  const int p = bn0 >> 8;   // 0:k 1:v 2:q 3:beta 4:alpha 5:gate
  float* outp = (p == 0) ? Kp : (p == 1) ? Vp : (p == 2) ? Qp : (p == 3) ? Bp : (p == 4) ? Ap : gate;
  #pragma unroll
  for (int rb = 0; rb < 2; ++rb) {
    #pragma unroll
    for (int cb = 0; cb < 4; ++cb) {
      int n = bn0 + cb * 16 + (lane & 15);
      int rem = n & 255;
      #pragma unroll
      for (int r = 0; r < 4; ++r) {
        int m = bm0 + w * 32 + rb * 16 + (lane >> 4) * 4 + r;
        float v = acc[rb][cb][r];
        if (p == 3) v = 1.0f / (1.0f + expf(-(v + b_beta[rem])));
        else if (p == 4) v = 1.0f / (1.0f + expf(-(v + b_alpha[rem])));
        if (p == 5) {
          gate[(size_t)m * SD + rem] = v;
        } else {
          int b = m >> 12, tt = m & 4095;
          int h = rem >> 5, d = rem & 31;
          outp[((size_t)(b * NH + h) * T_ + tt) * HD + d] = v;
        }
      }
    }
  }
}

// ---------------------------------------------------------------- k normalization
__global__ void __launch_bounds__(256) knorm(float* __restrict__ Kp) {
  int t = threadIdx.x;
  size_t row = (size_t)blockIdx.x * 8 + (t >> 5);
  int j = t & 31;
  float x = Kp[row * 32 + j];
  float s = x * x;
  #pragma unroll
  for (int m = 16; m >= 1; m >>= 1) s += __shfl_xor(s, m, 32);
  float inv = 1.0f / fmaxf(sqrtf(s), 1e-12f);
  Kp[row * 32 + j] = x * inv;
}

// ---------------------------------------------------------------- sequential scan
// One block per (b,h,half): 128 blocks x 64 threads (1 wave). Lane l owns row
// i = half*16 + (l>>2), columns (l&3)*8 .. +8 (8 floats of S in regs).
// Dot products reduce across the quad via DPP (VALU) — zero DS ops in chain.
// k/q/a/v/beta register-prefetched 1 step ahead; chunk staged to LDS via
// global_load_lds, double-buffered, counted vmcnt(20).
#define CH 32
#define NCH (T_/CH)
__global__ void __launch_bounds__(64) scan_kernel(
    const float* __restrict__ Kp, const float* __restrict__ Vp,
    const float* __restrict__ Qp, const float* __restrict__ Bp,
    const float* __restrict__ Ap, const float* __restrict__ state_in,
    float* __restrict__ ctx, float* __restrict__ Sfin)
{
  __shared__ float Kc[2][CH*HD], Qc[2][CH*HD], Ac[2][CH*HD], Vc[2][CH*HD], Bc[2][CH*HD]; // 40 KB
  const int bk = blockIdx.x;
  const int bh = bk >> 1, half = bk & 1;
  const int b = bh >> 3, h = bh & 7;
  const int l = threadIdx.x;
  const int i = half * 16 + (l >> 2);   // state row 0..31
  const int p = l & 3;                  // column part (8 cols)
  const size_t gbase = (size_t)bh * (T_ * HD);

  float S0 = state_in[(size_t)bh * 1024 + i * 32 + p * 8 + 0];
  float S1 = state_in[(size_t)bh * 1024 + i * 32 + p * 8 + 1];
  float S2 = state_in[(size_t)bh * 1024 + i * 32 + p * 8 + 2];
  float S3 = state_in[(size_t)bh * 1024 + i * 32 + p * 8 + 3];
  float S4 = state_in[(size_t)bh * 1024 + i * 32 + p * 8 + 4];
  float S5 = state_in[(size_t)bh * 1024 + i * 32 + p * 8 + 5];
  float S6 = state_in[(size_t)bh * 1024 + i * 32 + p * 8 + 6];
  float S7 = state_in[(size_t)bh * 1024 + i * 32 + p * 8 + 7];

  float* ctxp = ctx + (size_t)b * T_ * SD + h * HD + i;  // + t*SD per step

  auto stage = [&](int ci, int buf) {
    const float* kg = Kp + gbase + (size_t)ci * (CH * HD);
    const float* qg = Qp + gbase + (size_t)ci * (CH * HD);
    const float* ag = Ap + gbase + (size_t)ci * (CH * HD);
    const float* vg = Vp + gbase + (size_t)ci * (CH * HD);
    const float* bg = Bp + gbase + (size_t)ci * (CH * HD);
    #pragma unroll
    for (int it = 0; it < 4; ++it) {
      int u4 = (l + it * 64) * 4;   // float offset (lane-linear, matches HW dest lane*16B)
      int lb = it * 1024;           // LDS byte base (uniform)
      gload16(kg + u4, (char*)&Kc[buf][0] + lb);
      gload16(qg + u4, (char*)&Qc[buf][0] + lb);
      gload16(ag + u4, (char*)&Ac[buf][0] + lb);
      gload16(vg + u4, (char*)&Vc[buf][0] + lb);
      gload16(bg + u4, (char*)&Bc[buf][0] + lb);
    }
  };

  float4 k0a, k1a, q0a, q1a; float aa_, va_, ba_;
  float4 k0b, k1b, q0b, q1b; float ab_, vb_, bb_;

#define LDR(K0,K1,Q0,Q1,AA,VV,BB,buf,tc) do { \
    const float* kb_ = &Kc[buf][(tc)*HD]; \
    K0 = *(const float4*)(kb_ + p*8); K1 = *(const float4*)(kb_ + p*8 + 4); \
    const float* qb_ = &Qc[buf][(tc)*HD]; \
    Q0 = *(const float4*)(qb_ + p*8); Q1 = *(const float4*)(qb_ + p*8 + 4); \
    AA = Ac[buf][(tc)*HD + i]; VV = Vc[buf][(tc)*HD + i]; BB = Bc[buf][(tc)*HD + i]; \
  } while (0)

#define DOSTEP(K0,K1,Q0,Q1,AA,VV,BB,tg) do { \
    float m0 = S0 * K0.x, m1 = S1 * K0.y; \
    m0 = fmaf(S2, K0.z, m0); m1 = fmaf(S3, K0.w, m1); \
    m0 = fmaf(S4, K1.x, m0); m1 = fmaf(S5, K1.y, m1); \
    m0 = fmaf(S6, K1.z, m0); m1 = fmaf(S7, K1.w, m1); \
    float pd = qred(m0 + m1); \
    float u_ = BB * (VV - AA * pd); \
    S0 = fmaf(u_, K0.x, AA * S0); S1 = fmaf(u_, K0.y, AA * S1); \
    S2 = fmaf(u_, K0.z, AA * S2); S3 = fmaf(u_, K0.w, AA * S3); \
    S4 = fmaf(u_, K1.x, AA * S4); S5 = fmaf(u_, K1.y, AA * S5); \
    S6 = fmaf(u_, K1.z, AA * S6); S7 = fmaf(u_, K1.w, AA * S7); \
    float o0 = S0 * Q0.x, o1 = S1 * Q0.y; \
    o0 = fmaf(S2, Q0.z, o0); o1 = fmaf(S3, Q0.w, o1); \
    o0 = fmaf(S4, Q1.x, o0); o1 = fmaf(S5, Q1.y, o1); \
    o0 = fmaf(S6, Q1.z, o0); o1 = fmaf(S7, Q1.w, o1); \
    float od = qred(o0 + o1); \
    if (p == 0) ctxp[(size_t)(tg) * SD] = od; \
  } while (0)

  stage(0, 0);
  for (int ci = 0; ci < NCH; ++ci) {
    const int buf = ci & 1;
    if (ci + 1 < NCH) {
      stage(ci + 1, buf ^ 1);
      // 20 newest vmem ops = the prefetch just issued; everything older
      // (this chunk's stage + last chunk's ctx stores) must have retired.
      asm volatile("s_waitcnt vmcnt(20)" ::: "memory");
    } else {
      asm volatile("s_waitcnt vmcnt(0)" ::: "memory");
    }
    LDR(k0a, k1a, q0a, q1a, aa_, va_, ba_, buf, 0);
    #pragma unroll
    for (int tc = 0; tc < CH - 2; tc += 2) {
      LDR(k0b, k1b, q0b, q1b, ab_, vb_, bb_, buf, tc + 1);
      DOSTEP(k0a, k1a, q0a, q1a, aa_, va_, ba_, ci * CH + tc);
      LDR(k0a, k1a, q0a, q1a, aa_, va_, ba_, buf, tc + 2);
      DOSTEP(k0b, k1b, q0b, q1b, ab_, vb_, bb_, ci * CH + tc + 1);
    }
    LDR(k0b, k1b, q0b, q1b, ab_, vb_, bb_, buf, CH - 1);
    DOSTEP(k0a, k1a, q0a, q1a, aa_, va_, ba_, ci * CH + CH - 2);
    DOSTEP(k0b, k1b, q0b, q1b, ab_, vb_, bb_, ci * CH + CH - 1);
  }

  Sfin[(size_t)bh * 1024 + i * 32 + p * 8 + 0] = S0;
  Sfin[(size_t)bh * 1024 + i * 32 + p * 8 + 1] = S1;
  Sfin[(size_t)bh * 1024 + i * 32 + p * 8 + 2] = S2;
  Sfin[(size_t)bh * 1024 + i * 32 + p * 8 + 3] = S3;
  Sfin[(size_t)bh * 1024 + i * 32 + p * 8 + 4] = S4;
  Sfin[(size_t)bh * 1024 + i * 32 + p * 8 + 5] = S5;
  Sfin[(size_t)bh * 1024 + i * 32 + p * 8 + 6] = S6;
  Sfin[(size_t)bh * 1024 + i * 32 + p * 8 + 7] = S7;
#undef LDR
#undef DOSTEP
}

// ---------------------------------------------------------------- rmsnorm * silu(gate) -> bf16
__global__ void __launch_bounds__(256) rms_silu(
    const float* __restrict__ ctx, const float* __restrict__ gate,
    const float* __restrict__ norm_w, unsigned short* __restrict__ ctx2)
{
  size_t row = (size_t)blockIdx.x * 4 + (threadIdx.x >> 6);
  int lane = threadIdx.x & 63;
  const float4 x = *(const float4*)&ctx[row * SD + lane * 4];
  float s = x.x * x.x + x.y * x.y + x.z * x.z + x.w * x.w;
  #pragma unroll
  for (int m = 32; m >= 1; m >>= 1) s += __shfl_xor(s, m, 64);
  float rs = 1.0f / sqrtf(s * (1.0f / 256.0f) + 1e-6f);
  const float4 g = *(const float4*)&gate[row * SD + lane * 4];
  const float4 w = *(const float4*)&norm_w[lane * 4];
  ushort4 o;
  o.x = f2bf(x.x * rs * w.x * (g.x / (1.0f + expf(-g.x))));
  o.y = f2bf(x.y * rs * w.y * (g.y / (1.0f + expf(-g.y))));
  o.z = f2bf(x.z * rs * w.z * (g.z / (1.0f + expf(-g.z))));
  o.w = f2bf(x.w * rs * w.w * (g.w / (1.0f + expf(-g.w))));
  *(ushort4*)&ctx2[row * SD + lane * 4] = o;
}

// ---------------------------------------------------------------- output GEMM
__global__ void __launch_bounds__(256) out_gemm(
    const unsigned short* __restrict__ ctx2, const unsigned short* __restrict__ Wob,
    float* __restrict__ out)
{
  __shared__ unsigned short Asm[PM*PK];
  __shared__ unsigned short Bsm[PN*PK];
  const int t = threadIdx.x;
  const int w = t >> 6, lane = t & 63;
  const int bm0 = blockIdx.x * PM;
  const int bn0 = blockIdx.y * PN;

  f32x4 acc[2][4];
  #pragma unroll
  for (int i = 0; i < 2; ++i)
    #pragma unroll
    for (int j = 0; j < 4; ++j) acc[i][j] = (f32x4){0.f, 0.f, 0.f, 0.f};

  for (int k0 = 0; k0 < SD; k0 += PK) {
    #pragma unroll
    for (int it = 0; it < 4; ++it) {
      int unit = t + it * 256;
      int row = unit >> 3, seg = unit & 7;
      int dseg = seg ^ (row & 7);
      const unsigned short* g = ctx2 + (size_t)(bm0 + row) * SD + k0 + dseg * 8;
      gload16(g, (char*)Asm + (w * 1024 + it * 4096));
    }
    #pragma unroll
    for (int it = 0; it < 2; ++it) {
      int unit = t + it * 256;
      int n = unit >> 3, seg = unit & 7;
      int dseg = seg ^ (n & 7);
      const unsigned short* g = Wob + (size_t)(bn0 + n) * SD + k0 + dseg * 8;
      gload16(g, (char*)Bsm + (w * 1024 + it * 4096));
    }
    __syncthreads();
    #pragma unroll
    for (int ks = 0; ks < 2; ++ks) {
      short8 af[2], bfr[4];
      int u = ks * 4 + (lane >> 4);
      int slot = u ^ (lane & 7);
      #pragma unroll
      for (int rb = 0; rb < 2; ++rb) {
        int row = w * 32 + rb * 16 + (lane & 15);
        af[rb] = *(const short8*)((const char*)Asm + row * 128 + slot * 16);
      }
      #pragma unroll
      for (int cb = 0; cb < 4; ++cb) {
        int nn = cb * 16 + (lane & 15);
        bfr[cb] = *(const short8*)((const char*)Bsm + nn * 128 + slot * 16);
      }
      #pragma unroll
      for (int rb = 0; rb < 2; ++rb)
        #pragma unroll
        for (int cb = 0; cb < 4; ++cb)
          acc[rb][cb] = __builtin_amdgcn_mfma_f32_16x16x32_bf16(af[rb], bfr[cb], acc[rb][cb], 0, 0, 0);
    }
    __syncthreads();
  }
  #pragma unroll
  for (int rb = 0; rb < 2; ++rb)
    #pragma unroll
    for (int cb = 0; cb < 4; ++cb) {
      int n = bn0 + cb * 16 + (lane & 15);
      #pragma unroll
      for (int r = 0; r < 4; ++r) {
        int m = bm0 + w * 32 + rb * 16 + (lane >> 4) * 4 + r;
        out[(size_t)m * 512 + n] = acc[rb][cb][r];
      }
    }
}

// ---------------------------------------------------------------- launcher
extern "C" void kernel_launch(void* const* d_in, const int* in_sizes, int n_in,
                              void* d_out, int out_size, void* d_ws, size_t ws_size,
                              hipStream_t stream) {
  (void)in_sizes; (void)n_in; (void)out_size; (void)ws_size;
  const float* hidden  = (const float*)d_in[0];
  const float* state   = (const float*)d_in[1];
  const float* W_k     = (const float*)d_in[2];
  const float* W_v     = (const float*)d_in[3];
  const float* W_q     = (const float*)d_in[4];
  const float* W_beta  = (const float*)d_in[5];
  const float* b_beta  = (const float*)d_in[6];
  const float* W_alpha = (const float*)d_in[7];
  const float* b_alpha = (const float*)d_in[8];
  const float* W_out   = (const float*)d_in[9];
  const float* gate_W  = (const float*)d_in[10];
  const float* norm_w  = (const float*)d_in[11];
  float* out = (float*)d_out;

  char* ws = (char*)d_ws;
  unsigned short* hb  = (unsigned short*)(ws);
  unsigned short* Wc  = (unsigned short*)(ws + 33554432);
  unsigned short* Wob = (unsigned short*)(ws + 35127296);
  float* Kp   = (float*)(ws + 35389440);
  float* Vp   = Kp + 8388608;
  float* Qp   = Vp + 8388608;
  float* Bp   = Qp + 8388608;
  float* Ap   = Bp + 8388608;
  float* gate = Ap + 8388608;
  unsigned short* ctx2 = (unsigned short*)(ws + 236716032);
  float* ctx  = out;                 // fp32 scratch, overwritten by out_gemm
  float* Sfin = out + 16777216;      // final state output

  cvt_f32_bf16<<<2048, 256, 0, stream>>>(hidden, hb, M_TOK * HID / 4);
  cvt_f32_bf16<<<64, 256, 0, stream>>>(W_k,     Wc + 0 * 131072, 32768);
  cvt_f32_bf16<<<64, 256, 0, stream>>>(W_v,     Wc + 1 * 131072, 32768);
  cvt_f32_bf16<<<64, 256, 0, stream>>>(W_q,     Wc + 2 * 131072, 32768);
  cvt_f32_bf16<<<64, 256, 0, stream>>>(W_beta,  Wc + 3 * 131072, 32768);
  cvt_f32_bf16<<<64, 256, 0, stream>>>(W_alpha, Wc + 4 * 131072, 32768);
  cvt_f32_bf16<<<64, 256, 0, stream>>>(gate_W,  Wc + 5 * 131072, 32768);
  cvt_f32_bf16<<<64, 256, 0, stream>>>(W_out,   Wob, 32768);

  proj_gemm<<<dim3(256, 24), 256, 0, stream>>>(hb, Wc, b_beta, b_alpha, Kp, Vp, Qp, Bp, Ap, gate);
  knorm<<<32768, 256, 0, stream>>>(Kp);
  scan_kernel<<<128, 64, 0, stream>>>(Kp, Vp, Qp, Bp, Ap, state, ctx, Sfin);
  rms_silu<<<8192, 256, 0, stream>>>(ctx, gate, norm_w, ctx2);
  out_gemm<<<dim3(256, 8), 256, 0, stream>>>(ctx2, Wob, out);
}

// Round 3
// 727.221 us; speedup vs baseline: 1.8169x; 1.1807x over previous
//
#include <hip/hip_runtime.h>
#include <stdint.h>

// Problem constants
#define B_    8
#define T_    4096
#define HID   512
#define SD    256
#define NH    8
#define HD    32
#define M_TOK (B_*T_)          // 32768 tokens
#define NPROJ 1536             // 6 * 256 output channels (k,v,q,beta,alpha,gate)

typedef __attribute__((ext_vector_type(8))) short short8;   // 8 bf16 (4 VGPRs) — MFMA A/B frag
typedef __attribute__((ext_vector_type(4))) float f32x4;    // MFMA C/D frag
typedef __attribute__((ext_vector_type(2))) float f2;       // packed fp32 (v_pk_*_f32)

__device__ __forceinline__ unsigned short f2bf(float f) {
  uint32_t u = __float_as_uint(f);
  uint32_t r = (u + 0x7fffu + ((u >> 16) & 1u)) >> 16;
  return (unsigned short)r;
}

__device__ __forceinline__ void gload16(const void* g, void* l) {
  // async global->LDS, 16B per lane; LDS dest = wave-uniform base + lane*16
  __builtin_amdgcn_global_load_lds((const __attribute__((address_space(1))) void*)g,
                                   (__attribute__((address_space(3))) void*)l,
                                   16, 0, 0);
}

// butterfly sum across the 4 lanes of a quad — pure VALU (DPP), no DS pipe
__device__ __forceinline__ float qred(float x) {
  x += __int_as_float(__builtin_amdgcn_mov_dpp(__float_as_int(x), 0xB1, 0xF, 0xF, true)); // lane^1
  x += __int_as_float(__builtin_amdgcn_mov_dpp(__float_as_int(x), 0x4E, 0xF, 0xF, true)); // lane^2
  return x;
}

// ---------------------------------------------------------------- converts
__global__ void cvt_f32_bf16(const float* __restrict__ in, unsigned short* __restrict__ out, int n4) {
  int i = blockIdx.x * blockDim.x + threadIdx.x;
  int stride = gridDim.x * blockDim.x;
  for (; i < n4; i += stride) {
    float4 v = reinterpret_cast<const float4*>(in)[i];
    ushort4 o;
    o.x = f2bf(v.x); o.y = f2bf(v.y); o.z = f2bf(v.z); o.w = f2bf(v.w);
    reinterpret_cast<ushort4*>(out)[i] = o;
  }
}

// ---------------------------------------------------------------- projection GEMM
#define PM 128
#define PN 64
#define PK 64

__global__ void __launch_bounds__(256) proj_gemm(
    const unsigned short* __restrict__ hb, const unsigned short* __restrict__ Wc,
    const float* __restrict__ b_beta, const float* __restrict__ b_alpha,
    float* __restrict__ Kp, float* __restrict__ Qp,
    float* __restrict__ AVBf, float* __restrict__ gate)
{
  __shared__ unsigned short Asm[PM*PK];  // 16 KB
  __shared__ unsigned short Bsm[PN*PK];  // 8 KB
  const int t = threadIdx.x;
  const int w = t >> 6, lane = t & 63;
  const int bm0 = blockIdx.x * PM;
  const int bn0 = blockIdx.y * PN;

  f32x4 acc[2][4];
  #pragma unroll
  for (int i = 0; i < 2; ++i)
    #pragma unroll
    for (int j = 0; j < 4; ++j) acc[i][j] = (f32x4){0.f, 0.f, 0.f, 0.f};

  for (int k0 = 0; k0 < HID; k0 += PK) {
    #pragma unroll
    for (int it = 0; it < 4; ++it) {
      int unit = t + it * 256;
      int row = unit >> 3, seg = unit & 7;
      int dseg = seg ^ (row & 7);
      const unsigned short* g = hb + (size_t)(bm0 + row) * HID + k0 + dseg * 8;
      gload16(g, (char*)Asm + (w * 1024 + it * 4096));
    }
    #pragma unroll
    for (int it = 0; it < 2; ++it) {
      int unit = t + it * 256;
      int n = unit >> 3, seg = unit & 7;
      int dseg = seg ^ (n & 7);
      const unsigned short* g = Wc + (size_t)(bn0 + n) * HID + k0 + dseg * 8;
      gload16(g, (char*)Bsm + (w * 1024 + it * 4096));
    }
    __syncthreads();
    #pragma unroll
    for (int ks = 0; ks < 2; ++ks) {
      short8 af[2], bfr[4];
      int u = ks * 4 + (lane >> 4);
      int slot = u ^ (lane & 7);
      #pragma unroll
      for (int rb = 0; rb < 2; ++rb) {
        int row = w * 32 + rb * 16 + (lane & 15);
        af[rb] = *(const short8*)((const char*)Asm + row * 128 + slot * 16);
      }
      #pragma unroll
      for (int cb = 0; cb < 4; ++cb) {
        int nn = cb * 16 + (lane & 15);
        bfr[cb] = *(const short8*)((const char*)Bsm + nn * 128 + slot * 16);
      }
      #pragma unroll
      for (int rb = 0; rb < 2; ++rb)
        #pragma unroll
        for (int cb = 0; cb < 4; ++cb)
          acc[rb][cb] = __builtin_amdgcn_mfma_f32_16x16x32_bf16(af[rb], bfr[cb], acc[rb][cb], 0, 0, 0);
    }
    __syncthreads();
  }

  const int p = bn0 >> 8;   // 0:k 1:v 2:q 3:beta 4:alpha 5:gate
  #pragma unroll
  for (int rb = 0; rb < 2; ++rb) {
    #pragma unroll
    for (int cb = 0; cb < 4; ++cb) {
      int n = bn0 + cb * 16 + (lane & 15);
      int rem = n & 255;
      #pragma unroll
      for (int r = 0; r < 4; ++r) {
        int m = bm0 + w * 32 + rb * 16 + (lane >> 4) * 4 + r;
        float v = acc[rb][cb][r];
        int b = m >> 12, tt = m & 4095;
        int h = rem >> 5, d = rem & 31;
        size_t tok = ((size_t)(b * NH + h) * T_ + tt);
        if (p == 0) {
          Kp[tok * HD + d] = v;
        } else if (p == 2) {
          Qp[tok * HD + d] = v;
        } else if (p == 5) {
          gate[(size_t)m * SD + rem] = v;
        } else {
          float wv = v;
          if (p == 3) wv = 1.0f / (1.0f + expf(-(v + b_beta[rem])));
          if (p == 4) wv = 1.0f / (1.0f + expf(-(v + b_alpha[rem])));
          int comp = (p == 4) ? 0 : (p == 1) ? 1 : 2;   // (a, v, beta, pad)
          AVBf[(tok * HD + d) * 4 + comp] = wv;
        }
      }
    }
  }
}

// ---------------------------------------------------------------- k normalization
__global__ void __launch_bounds__(256) knorm(float* __restrict__ Kp) {
  int t = threadIdx.x;
  size_t row = (size_t)blockIdx.x * 8 + (t >> 5);
  int j = t & 31;
  float x = Kp[row * 32 + j];
  float s = x * x;
  #pragma unroll
  for (int m = 16; m >= 1; m >>= 1) s += __shfl_xor(s, m, 32);
  float inv = 1.0f / fmaxf(sqrtf(s), 1e-12f);
  Kp[row * 32 + j] = x * inv;
}

// ---------------------------------------------------------------- sequential scan
// One block per (b,h,half): 128 blocks x 64 threads. Lane l: row i = half*16 + (l>>2),
// column part p = l&3 (8 cols as 4 f2 regs). Quad DPP reduce; packed fp32 math.
// Per 4-step group: 20 ds_reads into NAMED regs, double-buffered (A/B sets).
// Chunk (32 steps) staged to LDS via global_load_lds one full chunk ahead,
// counted vmcnt(32) = 8 group-stores + 24 prefetch loads issued since.
#define CH 32
#define NCH (T_/CH)
__global__ void __launch_bounds__(64) scan_kernel(
    const float* __restrict__ Kp, const float* __restrict__ Qp,
    const float4* __restrict__ AVB, const float* __restrict__ state_in,
    float* __restrict__ ctx, float* __restrict__ Sfin)
{
  __shared__ float  Kc[2][CH*HD];   // 8 KB
  __shared__ float  Qc[2][CH*HD];   // 8 KB
  __shared__ float4 Vc[2][CH*HD];   // 32 KB
  const int bk = blockIdx.x;
  const int bh = bk >> 1, half = bk & 1;
  const int b = bh >> 3, h = bh & 7;
  const int l = threadIdx.x;
  const int i = half * 16 + (l >> 2);   // state row
  const int p = l & 3;                  // column part
  const bool isP0 = (p == 0), isP1 = (p == 1), isP2 = (p == 2), isP3 = (p == 3);

  const float*  Kg = Kp  + (size_t)bh * (T_ * HD);
  const float*  Qg = Qp  + (size_t)bh * (T_ * HD);
  const float4* Vg = AVB + (size_t)bh * (T_ * HD);

  f2 S01, S23, S45, S67;
  {
    const float* sp = state_in + (size_t)bh * 1024 + i * 32 + p * 8;
    float4 s0 = *(const float4*)sp, s1 = *(const float4*)(sp + 4);
    S01 = (f2){s0.x, s0.y}; S23 = (f2){s0.z, s0.w};
    S45 = (f2){s1.x, s1.y}; S67 = (f2){s1.z, s1.w};
  }

  float* ctxq = ctx + (size_t)b * T_ * SD + h * HD + i + (size_t)p * SD;
  float osel = 0.0f;

  auto stage = [&](int ci, int buf) {
    const float*  kg = Kg + (size_t)ci * (CH * HD);
    const float*  qg = Qg + (size_t)ci * (CH * HD);
    const float4* vg = Vg + (size_t)ci * (CH * HD);
    #pragma unroll
    for (int it = 0; it < 4; ++it) {
      int u4 = (l + it * 64) * 4;
      gload16(kg + u4, (char*)&Kc[buf][0] + it * 1024);
      gload16(qg + u4, (char*)&Qc[buf][0] + it * 1024);
    }
    #pragma unroll
    for (int it = 0; it < 16; ++it) {
      gload16(vg + (l + it * 64), (char*)&Vc[buf][0] + it * 1024);
    }
  };

#define LDSTEP(Ka,Kb,Qa,Qb,Vv,buf,T0) do { \
    Ka = *(const float4*)((const char*)&Kc[buf][0] + (T0)*128 + (p<<5)); \
    Kb = *(const float4*)((const char*)&Kc[buf][0] + (T0)*128 + (p<<5) + 16); \
    Qa = *(const float4*)((const char*)&Qc[buf][0] + (T0)*128 + (p<<5)); \
    Qb = *(const float4*)((const char*)&Qc[buf][0] + (T0)*128 + (p<<5) + 16); \
    Vv = *(const float4*)((const char*)&Vc[buf][0] + (T0)*512 + (i<<4)); \
  } while (0)

#define DOSTEP(Ka,Kb,Qa,Qb,Vv,J) do { \
    f2 d_ = (f2){Ka.x, Ka.y} * S01; \
    d_ = __builtin_elementwise_fma((f2){Ka.z, Ka.w}, S23, d_); \
    d_ = __builtin_elementwise_fma((f2){Kb.x, Kb.y}, S45, d_); \
    d_ = __builtin_elementwise_fma((f2){Kb.z, Kb.w}, S67, d_); \
    float pd_ = qred(d_.x + d_.y); \
    float u_ = Vv.z * fmaf(-Vv.x, pd_, Vv.y); \
    f2 A2_ = (f2){Vv.x, Vv.x}; \
    f2 U2_ = (f2){u_, u_}; \
    S01 = __builtin_elementwise_fma(A2_, S01, U2_ * (f2){Ka.x, Ka.y}); \
    S23 = __builtin_elementwise_fma(A2_, S23, U2_ * (f2){Ka.z, Ka.w}); \
    S45 = __builtin_elementwise_fma(A2_, S45, U2_ * (f2){Kb.x, Kb.y}); \
    S67 = __builtin_elementwise_fma(A2_, S67, U2_ * (f2){Kb.z, Kb.w}); \
    f2 o_ = (f2){Qa.x, Qa.y} * S01; \
    o_ = __builtin_elementwise_fma((f2){Qa.z, Qa.w}, S23, o_); \
    o_ = __builtin_elementwise_fma((f2){Qb.x, Qb.y}, S45, o_); \
    o_ = __builtin_elementwise_fma((f2){Qb.z, Qb.w}, S67, o_); \
    float od_ = qred(o_.x + o_.y); \
    const bool sel_ = (J)==0 ? isP0 : (J)==1 ? isP1 : (J)==2 ? isP2 : isP3; \
    osel = sel_ ? od_ : osel; \
  } while (0)

#define DECL4(S) float4 k##S##0a,k##S##0b,q##S##0a,q##S##0b,v##S##0, \
                        k##S##1a,k##S##1b,q##S##1a,q##S##1b,v##S##1, \
                        k##S##2a,k##S##2b,q##S##2a,q##S##2b,v##S##2, \
                        k##S##3a,k##S##3b,q##S##3a,q##S##3b,v##S##3;
  DECL4(A) DECL4(B)

#define LD4(S,buf,T0) \
    LDSTEP(k##S##0a,k##S##0b,q##S##0a,q##S##0b,v##S##0, buf, (T0)+0); \
    LDSTEP(k##S##1a,k##S##1b,q##S##1a,q##S##1b,v##S##1, buf, (T0)+1); \
    LDSTEP(k##S##2a,k##S##2b,q##S##2a,q##S##2b,v##S##2, buf, (T0)+2); \
    LDSTEP(k##S##3a,k##S##3b,q##S##3a,q##S##3b,v##S##3, buf, (T0)+3);

#define C4(S) \
    DOSTEP(k##S##0a,k##S##0b,q##S##0a,q##S##0b,v##S##0, 0); \
    DOSTEP(k##S##1a,k##S##1b,q##S##1a,q##S##1b,v##S##1, 1); \
    DOSTEP(k##S##2a,k##S##2b,q##S##2a,q##S##2b,v##S##2, 2); \
    DOSTEP(k##S##3a,k##S##3b,q##S##3a,q##S##3b,v##S##3, 3); \
    *ctxq = osel; ctxq += 4 * SD;

  stage(0, 0);
  stage(1, 1);
  #pragma unroll 1
  for (int ci = 0; ci < NCH; ++ci) {
    const int buf = ci & 1;
    if (ci == 0 || ci == NCH - 1) {
      asm volatile("s_waitcnt vmcnt(0)" ::: "memory");
    } else {
      // newer-than-stage(ci): 8 group-stores (chunk ci-1) + 24 loads (stage ci+1)
      asm volatile("s_waitcnt vmcnt(32)" ::: "memory");
    }
    LD4(A, buf, 0)
    LD4(B, buf, 4)
    C4(A)
    LD4(A, buf, 8)
    C4(B)
    LD4(B, buf, 12)
    C4(A)
    LD4(A, buf, 16)
    C4(B)
    LD4(B, buf, 20)
    C4(A)
    LD4(A, buf, 24)
    C4(B)
    LD4(B, buf, 28)
    C4(A)
    C4(B)
    // all ds_reads of this buffer retired before restaging it
    asm volatile("s_waitcnt lgkmcnt(0)" ::: "memory");
    if (ci + 2 < NCH) stage(ci + 2, buf);
  }

  {
    float* sp = Sfin + (size_t)bh * 1024 + i * 32 + p * 8;
    sp[0] = S01.x; sp[1] = S01.y; sp[2] = S23.x; sp[3] = S23.y;
    sp[4] = S45.x; sp[5] = S45.y; sp[6] = S67.x; sp[7] = S67.y;
  }
#undef LDSTEP
#undef DOSTEP
#undef DECL4
#undef LD4
#undef C4
}

// ---------------------------------------------------------------- rmsnorm * silu(gate) -> bf16
__global__ void __launch_bounds__(256) rms_silu(
    const float* __restrict__ ctx, const float* __restrict__ gate,
    const float* __restrict__ norm_w, unsigned short* __restrict__ ctx2)
{
  size_t row = (size_t)blockIdx.x * 4 + (threadIdx.x >> 6);
  int lane = threadIdx.x & 63;
  const float4 x = *(const float4*)&ctx[row * SD + lane * 4];
  float s = x.x * x.x + x.y * x.y + x.z * x.z + x.w * x.w;
  #pragma unroll
  for (int m = 32; m >= 1; m >>= 1) s += __shfl_xor(s, m, 64);
  float rs = 1.0f / sqrtf(s * (1.0f / 256.0f) + 1e-6f);
  const float4 g = *(const float4*)&gate[row * SD + lane * 4];
  const float4 w = *(const float4*)&norm_w[lane * 4];
  ushort4 o;
  o.x = f2bf(x.x * rs * w.x * (g.x / (1.0f + expf(-g.x))));
  o.y = f2bf(x.y * rs * w.y * (g.y / (1.0f + expf(-g.y))));
  o.z = f2bf(x.z * rs * w.z * (g.z / (1.0f + expf(-g.z))));
  o.w = f2bf(x.w * rs * w.w * (g.w / (1.0f + expf(-g.w))));
  *(ushort4*)&ctx2[row * SD + lane * 4] = o;
}

// ---------------------------------------------------------------- output GEMM
__global__ void __launch_bounds__(256) out_gemm(
    const unsigned short* __restrict__ ctx2, const unsigned short* __restrict__ Wob,
    float* __restrict__ out)
{
  __shared__ unsigned short Asm[PM*PK];
  __shared__ unsigned short Bsm[PN*PK];
  const int t = threadIdx.x;
  const int w = t >> 6, lane = t & 63;
  const int bm0 = blockIdx.x * PM;
  const int bn0 = blockIdx.y * PN;

  f32x4 acc[2][4];
  #pragma unroll
  for (int i = 0; i < 2; ++i)
    #pragma unroll
    for (int j = 0; j < 4; ++j) acc[i][j] = (f32x4){0.f, 0.f, 0.f, 0.f};

  for (int k0 = 0; k0 < SD; k0 += PK) {
    #pragma unroll
    for (int it = 0; it < 4; ++it) {
      int unit = t + it * 256;
      int row = unit >> 3, seg = unit & 7;
      int dseg = seg ^ (row & 7);
      const unsigned short* g = ctx2 + (size_t)(bm0 + row) * SD + k0 + dseg * 8;
      gload16(g, (char*)Asm + (w * 1024 + it * 4096));
    }
    #pragma unroll
    for (int it = 0; it < 2; ++it) {
      int unit = t + it * 256;
      int n = unit >> 3, seg = unit & 7;
      int dseg = seg ^ (n & 7);
      const unsigned short* g = Wob + (size_t)(bn0 + n) * SD + k0 + dseg * 8;
      gload16(g, (char*)Bsm + (w * 1024 + it * 4096));
    }
    __syncthreads();
    #pragma unroll
    for (int ks = 0; ks < 2; ++ks) {
      short8 af[2], bfr[4];
      int u = ks * 4 + (lane >> 4);
      int slot = u ^ (lane & 7);
      #pragma unroll
      for (int rb = 0; rb < 2; ++rb) {
        int row = w * 32 + rb * 16 + (lane & 15);
        af[rb] = *(const short8*)((const char*)Asm + row * 128 + slot * 16);
      }
      #pragma unroll
      for (int cb = 0; cb < 4; ++cb) {
        int nn = cb * 16 + (lane & 15);
        bfr[cb] = *(const short8*)((const char*)Bsm + nn * 128 + slot * 16);
      }
      #pragma unroll
      for (int rb = 0; rb < 2; ++rb)
        #pragma unroll
        for (int cb = 0; cb < 4; ++cb)
          acc[rb][cb] = __builtin_amdgcn_mfma_f32_16x16x32_bf16(af[rb], bfr[cb], acc[rb][cb], 0, 0, 0);
    }
    __syncthreads();
  }
  #pragma unroll
  for (int rb = 0; rb < 2; ++rb)
    #pragma unroll
    for (int cb = 0; cb < 4; ++cb) {
      int n = bn0 + cb * 16 + (lane & 15);
      #pragma unroll
      for (int r = 0; r < 4; ++r) {
        int m = bm0 + w * 32 + rb * 16 + (lane >> 4) * 4 + r;
        out[(size_t)m * 512 + n] = acc[rb][cb][r];
      }
    }
}

// ---------------------------------------------------------------- launcher
// ws layout (bytes), total 253,493,248:
//   hb   bf16 [32768][512]            @ 0
//   Wc   bf16 [1536][512]             @ 33,554,432
//   Wob  bf16 [512][256]              @ 35,127,296
//   Kp   f32  [64][4096][32]          @ 35,389,440
//   Qp   f32  [64][4096][32]          @ 68,943,872
//   AVB  f32x4 [64][4096][32]         @ 102,498,304   (a, v, beta, pad)
//   ctx2 bf16 [32768][256]            @ 236,716,032
// d_out reuse: ctx f32 [32768][256] @ 0; gate f32 [32768][256] @ +8388608 floats
// (both overwritten later by out_gemm); Sfin @ +16777216 floats.
extern "C" void kernel_launch(void* const* d_in, const int* in_sizes, int n_in,
                              void* d_out, int out_size, void* d_ws, size_t ws_size,
                              hipStream_t stream) {
  (void)in_sizes; (void)n_in; (void)out_size; (void)ws_size;
  const float* hidden  = (const float*)d_in[0];
  const float* state   = (const float*)d_in[1];
  const float* W_k     = (const float*)d_in[2];
  const float* W_v     = (const float*)d_in[3];
  const float* W_q     = (const float*)d_in[4];
  const float* W_beta  = (const float*)d_in[5];
  const float* b_beta  = (const float*)d_in[6];
  const float* W_alpha = (const float*)d_in[7];
  const float* b_alpha = (const float*)d_in[8];
  const float* W_out   = (const float*)d_in[9];
  const float* gate_W  = (const float*)d_in[10];
  const float* norm_w  = (const float*)d_in[11];
  float* out = (float*)d_out;

  char* ws = (char*)d_ws;
  unsigned short* hb  = (unsigned short*)(ws);
  unsigned short* Wc  = (unsigned short*)(ws + 33554432);
  unsigned short* Wob = (unsigned short*)(ws + 35127296);
  float* Kp   = (float*)(ws + 35389440);
  float* Qp   = (float*)(ws + 68943872);
  float* AVBf = (float*)(ws + 102498304);
  unsigned short* ctx2 = (unsigned short*)(ws + 236716032);
  float* ctx  = out;                 // fp32 scratch, overwritten by out_gemm
  float* gate = out + 8388608;       // fp32 scratch, overwritten by out_gemm
  float* Sfin = out + 16777216;      // final state output

  cvt_f32_bf16<<<2048, 256, 0, stream>>>(hidden, hb, M_TOK * HID / 4);
  cvt_f32_bf16<<<64, 256, 0, stream>>>(W_k,     Wc + 0 * 131072, 32768);
  cvt_f32_bf16<<<64, 256, 0, stream>>>(W_v,     Wc + 1 * 131072, 32768);
  cvt_f32_bf16<<<64, 256, 0, stream>>>(W_q,     Wc + 2 * 131072, 32768);
  cvt_f32_bf16<<<64, 256, 0, stream>>>(W_beta,  Wc + 3 * 131072, 32768);
  cvt_f32_bf16<<<64, 256, 0, stream>>>(W_alpha, Wc + 4 * 131072, 32768);
  cvt_f32_bf16<<<64, 256, 0, stream>>>(gate_W,  Wc + 5 * 131072, 32768);
  cvt_f32_bf16<<<64, 256, 0, stream>>>(W_out,   Wob, 32768);

  proj_gemm<<<dim3(256, 24), 256, 0, stream>>>(hb, Wc, b_beta, b_alpha, Kp, Qp, AVBf, gate);
  knorm<<<32768, 256, 0, stream>>>(Kp);
  scan_kernel<<<128, 64, 0, stream>>>(Kp, Qp, (const float4*)AVBf, state, ctx, Sfin);
  rms_silu<<<8192, 256, 0, stream>>>(ctx, gate, norm_w, ctx2);
  out_gemm<<<dim3(256, 8), 256, 0, stream>>>(ctx2, Wob, out);
}

// Round 4
// 604.779 us; speedup vs baseline: 2.1847x; 1.2025x over previous
//
#include <hip/hip_runtime.h>
#include <stdint.h>

// Problem constants
#define B_    8
#define T_    4096
#define HID   512
#define SD    256
#define NH    8
#define HD    32
#define M_TOK (B_*T_)          // 32768 tokens
#define NPROJ 1536             // 6 * 256 output channels (k,v,q,beta,alpha,gate)

typedef __attribute__((ext_vector_type(8))) short short8;   // 8 bf16 (4 VGPRs) — MFMA A/B frag
typedef __attribute__((ext_vector_type(4))) float f32x4;    // MFMA C/D frag
typedef __attribute__((ext_vector_type(4))) float f4;       // asm ds_read_b128 dst
typedef __attribute__((ext_vector_type(2))) float f2;       // packed fp32 (v_pk_*_f32)

__device__ __forceinline__ unsigned short f2bf(float f) {
  uint32_t u = __float_as_uint(f);
  uint32_t r = (u + 0x7fffu + ((u >> 16) & 1u)) >> 16;
  return (unsigned short)r;
}

__device__ __forceinline__ void gload16(const void* g, void* l) {
  // async global->LDS, 16B per lane; LDS dest = wave-uniform base + lane*16
  __builtin_amdgcn_global_load_lds((const __attribute__((address_space(1))) void*)g,
                                   (__attribute__((address_space(3))) void*)l,
                                   16, 0, 0);
}

// butterfly sum across the 4 lanes of a quad — pure VALU (DPP), no DS pipe
__device__ __forceinline__ float qred(float x) {
  x += __int_as_float(__builtin_amdgcn_mov_dpp(__float_as_int(x), 0xB1, 0xF, 0xF, true)); // lane^1
  x += __int_as_float(__builtin_amdgcn_mov_dpp(__float_as_int(x), 0x4E, 0xF, 0xF, true)); // lane^2
  return x;
}

// ---------------------------------------------------------------- converts
__global__ void cvt_f32_bf16(const float* __restrict__ in, unsigned short* __restrict__ out, int n4) {
  int i = blockIdx.x * blockDim.x + threadIdx.x;
  int stride = gridDim.x * blockDim.x;
  for (; i < n4; i += stride) {
    float4 v = reinterpret_cast<const float4*>(in)[i];
    ushort4 o;
    o.x = f2bf(v.x); o.y = f2bf(v.y); o.z = f2bf(v.z); o.w = f2bf(v.w);
    reinterpret_cast<ushort4*>(out)[i] = o;
  }
}

// ---------------------------------------------------------------- projection GEMM
#define PM 128
#define PN 64
#define PK 64

__global__ void __launch_bounds__(256) proj_gemm(
    const unsigned short* __restrict__ hb, const unsigned short* __restrict__ Wc,
    const float* __restrict__ b_beta, const float* __restrict__ b_alpha,
    float* __restrict__ Kp, float* __restrict__ Qp,
    float* __restrict__ AVBf, float* __restrict__ gate)
{
  __shared__ unsigned short Asm[PM*PK];  // 16 KB
  __shared__ unsigned short Bsm[PN*PK];  // 8 KB
  const int t = threadIdx.x;
  const int w = t >> 6, lane = t & 63;
  const int bm0 = blockIdx.x * PM;
  const int bn0 = blockIdx.y * PN;

  f32x4 acc[2][4];
  #pragma unroll
  for (int i = 0; i < 2; ++i)
    #pragma unroll
    for (int j = 0; j < 4; ++j) acc[i][j] = (f32x4){0.f, 0.f, 0.f, 0.f};

  for (int k0 = 0; k0 < HID; k0 += PK) {
    #pragma unroll
    for (int it = 0; it < 4; ++it) {
      int unit = t + it * 256;
      int row = unit >> 3, seg = unit & 7;
      int dseg = seg ^ (row & 7);
      const unsigned short* g = hb + (size_t)(bm0 + row) * HID + k0 + dseg * 8;
      gload16(g, (char*)Asm + (w * 1024 + it * 4096));
    }
    #pragma unroll
    for (int it = 0; it < 2; ++it) {
      int unit = t + it * 256;
      int n = unit >> 3, seg = unit & 7;
      int dseg = seg ^ (n & 7);
      const unsigned short* g = Wc + (size_t)(bn0 + n) * HID + k0 + dseg * 8;
      gload16(g, (char*)Bsm + (w * 1024 + it * 4096));
    }
    __syncthreads();
    #pragma unroll
    for (int ks = 0; ks < 2; ++ks) {
      short8 af[2], bfr[4];
      int u = ks * 4 + (lane >> 4);
      int slot = u ^ (lane & 7);
      #pragma unroll
      for (int rb = 0; rb < 2; ++rb) {
        int row = w * 32 + rb * 16 + (lane & 15);
        af[rb] = *(const short8*)((const char*)Asm + row * 128 + slot * 16);
      }
      #pragma unroll
      for (int cb = 0; cb < 4; ++cb) {
        int nn = cb * 16 + (lane & 15);
        bfr[cb] = *(const short8*)((const char*)Bsm + nn * 128 + slot * 16);
      }
      #pragma unroll
      for (int rb = 0; rb < 2; ++rb)
        #pragma unroll
        for (int cb = 0; cb < 4; ++cb)
          acc[rb][cb] = __builtin_amdgcn_mfma_f32_16x16x32_bf16(af[rb], bfr[cb], acc[rb][cb], 0, 0, 0);
    }
    __syncthreads();
  }

  const int p = bn0 >> 8;   // 0:k 1:v 2:q 3:beta 4:alpha 5:gate
  #pragma unroll
  for (int rb = 0; rb < 2; ++rb) {
    #pragma unroll
    for (int cb = 0; cb < 4; ++cb) {
      int n = bn0 + cb * 16 + (lane & 15);
      int rem = n & 255;
      #pragma unroll
      for (int r = 0; r < 4; ++r) {
        int m = bm0 + w * 32 + rb * 16 + (lane >> 4) * 4 + r;
        float v = acc[rb][cb][r];
        int b = m >> 12, tt = m & 4095;
        int h = rem >> 5, d = rem & 31;
        size_t tok = ((size_t)(b * NH + h) * T_ + tt);
        if (p == 0) {
          Kp[tok * HD + d] = v;
        } else if (p == 2) {
          Qp[tok * HD + d] = v;
        } else if (p == 5) {
          gate[(size_t)m * SD + rem] = v;
        } else {
          float wv = v;
          if (p == 3) wv = 1.0f / (1.0f + expf(-(v + b_beta[rem])));
          if (p == 4) wv = 1.0f / (1.0f + expf(-(v + b_alpha[rem])));
          int comp = (p == 4) ? 0 : (p == 1) ? 1 : 2;   // (a, v, beta, pad)
          AVBf[(tok * HD + d) * 4 + comp] = wv;
        }
      }
    }
  }
}

// ---------------------------------------------------------------- k normalization
__global__ void __launch_bounds__(256) knorm(float* __restrict__ Kp) {
  int t = threadIdx.x;
  size_t row = (size_t)blockIdx.x * 8 + (t >> 5);
  int j = t & 31;
  float x = Kp[row * 32 + j];
  float s = x * x;
  #pragma unroll
  for (int m = 16; m >= 1; m >>= 1) s += __shfl_xor(s, m, 32);
  float inv = 1.0f / fmaxf(sqrtf(s), 1e-12f);
  Kp[row * 32 + j] = x * inv;
}

// ---------------------------------------------------------------- sequential scan
// 128 blocks x 64 threads; lane l: row i = half*16 + (l>>2), part p = l&3 (8 cols).
// Inner loop: asm-pinned ds_read_b128 into named regs, 2-step groups, depth-1
// pipeline with exact lgkmcnt(10) waits + sched_barrier (compiler cannot
// re-expose LDS latency). Chunk (32 steps) staged via global_load_lds one
// chunk ahead; counted vmcnt(32) = 8 group-stores + 24 prefetch loads.
// LDS layout (single block, byte offsets): K[2][4KB] @0, Q[2][4KB] @8192,
// V(avb)[2][16KB] @16384. Total 48KB.
#define CH 32
#define NCH (T_/CH)

#define DSR(dst, areg, imm) \
  asm volatile("ds_read_b128 %0, %1 offset:%c2" : "=v"(dst) : "v"(areg), "i"(imm))

#define WK10 do { asm volatile("s_waitcnt lgkmcnt(10)" ::: "memory"); __builtin_amdgcn_sched_barrier(0); } while(0)
#define WK0  do { asm volatile("s_waitcnt lgkmcnt(0)"  ::: "memory"); __builtin_amdgcn_sched_barrier(0); } while(0)

#define SHUF2(V,A,B) __builtin_shufflevector(V, V, A, B)

__global__ void __launch_bounds__(64) scan_kernel(
    const float* __restrict__ Kp, const float* __restrict__ Qp,
    const float4* __restrict__ AVB, const float* __restrict__ state_in,
    float* __restrict__ ctx, float* __restrict__ Sfin)
{
  __shared__ __align__(16) char Lds[49152];
  const int bk = blockIdx.x;
  const int bh = bk >> 1, half = bk & 1;
  const int b = bh >> 3, h = bh & 7;
  const int l = threadIdx.x;
  const int i = half * 16 + (l >> 2);   // state row
  const int p = l & 3;                  // column part
  const bool isP0 = (p == 0), isP1 = (p == 1), isP2 = (p == 2), isP3 = (p == 3);

  const float*  Kg = Kp  + (size_t)bh * (T_ * HD);
  const float*  Qg = Qp  + (size_t)bh * (T_ * HD);
  const float4* Vg = AVB + (size_t)bh * (T_ * HD);

  f2 S01, S23, S45, S67;
  {
    const float* sp = state_in + (size_t)bh * 1024 + i * 32 + p * 8;
    float4 s0 = *(const float4*)sp, s1 = *(const float4*)(sp + 4);
    S01 = (f2){s0.x, s0.y}; S23 = (f2){s0.z, s0.w};
    S45 = (f2){s1.x, s1.y}; S67 = (f2){s1.z, s1.w};
  }

  float* ctxq = ctx + (size_t)b * T_ * SD + h * HD + i + (size_t)p * SD;
  float osel = 0.0f;

  const uint32_t lds0 = (uint32_t)(uintptr_t)(__attribute__((address_space(3))) char*)&Lds[0];
  const uint32_t a_kq = lds0 + p * 32;   // per-lane K/Q fragment base
  const uint32_t a_v  = lds0 + i * 16;   // per-lane AVB base

  auto stage = [&](int c2, int buf) {
    const float*  kg = Kg + (size_t)c2 * (CH * HD);
    const float*  qg = Qg + (size_t)c2 * (CH * HD);
    const float4* vg = Vg + (size_t)c2 * (CH * HD);
    #pragma unroll
    for (int it = 0; it < 4; ++it) {
      gload16(kg + (size_t)(l + it * 64) * 4, Lds + buf * 4096 + it * 1024);
      gload16(qg + (size_t)(l + it * 64) * 4, Lds + 8192 + buf * 4096 + it * 1024);
    }
    #pragma unroll
    for (int it = 0; it < 16; ++it) {
      gload16(vg + (l + it * 64), Lds + 16384 + buf * 16384 + it * 1024);
    }
  };

#define DOSTEP(KA,KB,QA,QB,VV,J) do { \
    f2 kl_ = SHUF2(KA,0,1), kh_ = SHUF2(KA,2,3); \
    f2 kl2_ = SHUF2(KB,0,1), kh2_ = SHUF2(KB,2,3); \
    f2 m1_ = kl_*S01, m2_ = kh_*S23, m3_ = kl2_*S45, m4_ = kh2_*S67; \
    f2 hh_ = (m1_+m2_)+(m3_+m4_); \
    float pd_ = qred(hh_.x + hh_.y); \
    float bv_ = VV.y * VV.z, ba_ = VV.x * VV.z; \
    float u_ = fmaf(-ba_, pd_, bv_); \
    f2 A2_ = (f2){VV.x, VV.x}; \
    f2 U2_ = (f2){u_, u_}; \
    S01 = __builtin_elementwise_fma(U2_, kl_,  A2_*S01); \
    S23 = __builtin_elementwise_fma(U2_, kh_,  A2_*S23); \
    S45 = __builtin_elementwise_fma(U2_, kl2_, A2_*S45); \
    S67 = __builtin_elementwise_fma(U2_, kh2_, A2_*S67); \
    f2 o1_ = SHUF2(QA,0,1)*S01, o2_ = SHUF2(QA,2,3)*S23; \
    f2 o3_ = SHUF2(QB,0,1)*S45, o4_ = SHUF2(QB,2,3)*S67; \
    f2 oh_ = (o1_+o2_)+(o3_+o4_); \
    float od_ = qred(oh_.x + oh_.y); \
    const bool sel_ = (J)==0 ? isP0 : (J)==1 ? isP1 : (J)==2 ? isP2 : isP3; \
    osel = sel_ ? od_ : osel; \
  } while (0)

  // named regs: 2 sets (A/B) x 2 steps x 5 frags = 80 VGPR pinned
  f4 kaA0,kbA0,qaA0,qbA0,vvA0, kaA1,kbA1,qaA1,qbA1,vvA1;
  f4 kaB0,kbB0,qaB0,qbB0,vvB0, kaB1,kbB1,qaB1,qbB1,vvB1;

#define R2(S, BUF, G) do { \
    DSR(ka##S##0, a_kq, (BUF)*4096 + (2*(G))*128); \
    DSR(kb##S##0, a_kq, (BUF)*4096 + (2*(G))*128 + 16); \
    DSR(qa##S##0, a_kq, 8192 + (BUF)*4096 + (2*(G))*128); \
    DSR(qb##S##0, a_kq, 8192 + (BUF)*4096 + (2*(G))*128 + 16); \
    DSR(vv##S##0, a_v,  16384 + (BUF)*16384 + (2*(G))*512); \
    DSR(ka##S##1, a_kq, (BUF)*4096 + (2*(G)+1)*128); \
    DSR(kb##S##1, a_kq, (BUF)*4096 + (2*(G)+1)*128 + 16); \
    DSR(qa##S##1, a_kq, 8192 + (BUF)*4096 + (2*(G)+1)*128); \
    DSR(qb##S##1, a_kq, 8192 + (BUF)*4096 + (2*(G)+1)*128 + 16); \
    DSR(vv##S##1, a_v,  16384 + (BUF)*16384 + (2*(G)+1)*512); \
  } while (0)

#define C2(S, G) do { \
    DOSTEP(ka##S##0,kb##S##0,qa##S##0,qb##S##0,vvA_ALIAS##S##0, (2*(G))&3); \
  } while (0)
  // (C2 defined properly below — alias trick not needed)
#undef C2
#define C2(S, G) do { \
    DOSTEP(ka##S##0,kb##S##0,qa##S##0,qb##S##0,vv##S##0, (2*(G))&3); \
    DOSTEP(ka##S##1,kb##S##1,qa##S##1,qb##S##1,vv##S##1, (2*(G)+1)&3); \
    if (((G)&1) == 1) { *ctxq = osel; ctxq += 4*SD; } \
  } while (0)

#define CHUNKBODY(BUF) do { \
    if (ci == 0 || ci == NCH-1) { asm volatile("s_waitcnt vmcnt(0)" ::: "memory"); } \
    else                        { asm volatile("s_waitcnt vmcnt(32)" ::: "memory"); } \
    __builtin_amdgcn_sched_barrier(0); \
    R2(A,BUF,0); R2(B,BUF,1); \
    WK10; C2(A,0);  R2(A,BUF,2); \
    WK10; C2(B,1);  R2(B,BUF,3); \
    WK10; C2(A,2);  R2(A,BUF,4); \
    WK10; C2(B,3);  R2(B,BUF,5); \
    WK10; C2(A,4);  R2(A,BUF,6); \
    WK10; C2(B,5);  R2(B,BUF,7); \
    WK10; C2(A,6);  R2(A,BUF,8); \
    WK10; C2(B,7);  R2(B,BUF,9); \
    WK10; C2(A,8);  R2(A,BUF,10); \
    WK10; C2(B,9);  R2(B,BUF,11); \
    WK10; C2(A,10); R2(A,BUF,12); \
    WK10; C2(B,11); R2(B,BUF,13); \
    WK10; C2(A,12); R2(A,BUF,14); \
    WK10; C2(B,13); R2(B,BUF,15); \
    WK10; C2(A,14); \
    WK0;  C2(B,15); \
    if (ci + 2 < NCH) stage(ci + 2, BUF); \
  } while (0)

  stage(0, 0);
  stage(1, 1);
  int ci;
  #pragma unroll 1
  for (int cp = 0; cp < NCH / 2; ++cp) {
    ci = cp * 2;
    CHUNKBODY(0);
    ci = cp * 2 + 1;
    CHUNKBODY(1);
  }

  {
    float* sp = Sfin + (size_t)bh * 1024 + i * 32 + p * 8;
    sp[0] = S01.x; sp[1] = S01.y; sp[2] = S23.x; sp[3] = S23.y;
    sp[4] = S45.x; sp[5] = S45.y; sp[6] = S67.x; sp[7] = S67.y;
  }
#undef DOSTEP
#undef R2
#undef C2
#undef CHUNKBODY
}

// ---------------------------------------------------------------- rmsnorm * silu(gate) -> bf16
__global__ void __launch_bounds__(256) rms_silu(
    const float* __restrict__ ctx, const float* __restrict__ gate,
    const float* __restrict__ norm_w, unsigned short* __restrict__ ctx2)
{
  size_t row = (size_t)blockIdx.x * 4 + (threadIdx.x >> 6);
  int lane = threadIdx.x & 63;
  const float4 x = *(const float4*)&ctx[row * SD + lane * 4];
  float s = x.x * x.x + x.y * x.y + x.z * x.z + x.w * x.w;
  #pragma unroll
  for (int m = 32; m >= 1; m >>= 1) s += __shfl_xor(s, m, 64);
  float rs = 1.0f / sqrtf(s * (1.0f / 256.0f) + 1e-6f);
  const float4 g = *(const float4*)&gate[row * SD + lane * 4];
  const float4 w = *(const float4*)&norm_w[lane * 4];
  ushort4 o;
  o.x = f2bf(x.x * rs * w.x * (g.x / (1.0f + expf(-g.x))));
  o.y = f2bf(x.y * rs * w.y * (g.y / (1.0f + expf(-g.y))));
  o.z = f2bf(x.z * rs * w.z * (g.z / (1.0f + expf(-g.z))));
  o.w = f2bf(x.w * rs * w.w * (g.w / (1.0f + expf(-g.w))));
  *(ushort4*)&ctx2[row * SD + lane * 4] = o;
}

// ---------------------------------------------------------------- output GEMM
__global__ void __launch_bounds__(256) out_gemm(
    const unsigned short* __restrict__ ctx2, const unsigned short* __restrict__ Wob,
    float* __restrict__ out)
{
  __shared__ unsigned short Asm[PM*PK];
  __shared__ unsigned short Bsm[PN*PK];
  const int t = threadIdx.x;
  const int w = t >> 6, lane = t & 63;
  const int bm0 = blockIdx.x * PM;
  const int bn0 = blockIdx.y * PN;

  f32x4 acc[2][4];
  #pragma unroll
  for (int i = 0; i < 2; ++i)
    #pragma unroll
    for (int j = 0; j < 4; ++j) acc[i][j] = (f32x4){0.f, 0.f, 0.f, 0.f};

  for (int k0 = 0; k0 < SD; k0 += PK) {
    #pragma unroll
    for (int it = 0; it < 4; ++it) {
      int unit = t + it * 256;
      int row = unit >> 3, seg = unit & 7;
      int dseg = seg ^ (row & 7);
      const unsigned short* g = ctx2 + (size_t)(bm0 + row) * SD + k0 + dseg * 8;
      gload16(g, (char*)Asm + (w * 1024 + it * 4096));
    }
    #pragma unroll
    for (int it = 0; it < 2; ++it) {
      int unit = t + it * 256;
      int n = unit >> 3, seg = unit & 7;
      int dseg = seg ^ (n & 7);
      const unsigned short* g = Wob + (size_t)(bn0 + n) * SD + k0 + dseg * 8;
      gload16(g, (char*)Bsm + (w * 1024 + it * 4096));
    }
    __syncthreads();
    #pragma unroll
    for (int ks = 0; ks < 2; ++ks) {
      short8 af[2], bfr[4];
      int u = ks * 4 + (lane >> 4);
      int slot = u ^ (lane & 7);
      #pragma unroll
      for (int rb = 0; rb < 2; ++rb) {
        int row = w * 32 + rb * 16 + (lane & 15);
        af[rb] = *(const short8*)((const char*)Asm + row * 128 + slot * 16);
      }
      #pragma unroll
      for (int cb = 0; cb < 4; ++cb) {
        int nn = cb * 16 + (lane & 15);
        bfr[cb] = *(const short8*)((const char*)Bsm + nn * 128 + slot * 16);
      }
      #pragma unroll
      for (int rb = 0; rb < 2; ++rb)
        #pragma unroll
        for (int cb = 0; cb < 4; ++cb)
          acc[rb][cb] = __builtin_amdgcn_mfma_f32_16x16x32_bf16(af[rb], bfr[cb], acc[rb][cb], 0, 0, 0);
    }
    __syncthreads();
  }
  #pragma unroll
  for (int rb = 0; rb < 2; ++rb)
    #pragma unroll
    for (int cb = 0; cb < 4; ++cb) {
      int n = bn0 + cb * 16 + (lane & 15);
      #pragma unroll
      for (int r = 0; r < 4; ++r) {
        int m = bm0 + w * 32 + rb * 16 + (lane >> 4) * 4 + r;
        out[(size_t)m * 512 + n] = acc[rb][cb][r];
      }
    }
}

// ---------------------------------------------------------------- launcher
// ws layout (bytes), total 253,493,248:
//   hb   bf16 [32768][512]            @ 0
//   Wc   bf16 [1536][512]             @ 33,554,432
//   Wob  bf16 [512][256]              @ 35,127,296
//   Kp   f32  [64][4096][32]          @ 35,389,440
//   Qp   f32  [64][4096][32]          @ 68,943,872
//   AVB  f32x4 [64][4096][32]         @ 102,498,304   (a, v, beta, pad)
//   ctx2 bf16 [32768][256]            @ 236,716,032
// d_out reuse: ctx f32 [32768][256] @ 0; gate f32 [32768][256] @ +8388608 floats
// (both overwritten later by out_gemm); Sfin @ +16777216 floats.
extern "C" void kernel_launch(void* const* d_in, const int* in_sizes, int n_in,
                              void* d_out, int out_size, void* d_ws, size_t ws_size,
                              hipStream_t stream) {
  (void)in_sizes; (void)n_in; (void)out_size; (void)ws_size;
  const float* hidden  = (const float*)d_in[0];
  const float* state   = (const float*)d_in[1];
  const float* W_k     = (const float*)d_in[2];
  const float* W_v     = (const float*)d_in[3];
  const float* W_q     = (const float*)d_in[4];
  const float* W_beta  = (const float*)d_in[5];
  const float* b_beta  = (const float*)d_in[6];
  const float* W_alpha = (const float*)d_in[7];
  const float* b_alpha = (const float*)d_in[8];
  const float* W_out   = (const float*)d_in[9];
  const float* gate_W  = (const float*)d_in[10];
  const float* norm_w  = (const float*)d_in[11];
  float* out = (float*)d_out;

  char* ws = (char*)d_ws;
  unsigned short* hb  = (unsigned short*)(ws);
  unsigned short* Wc  = (unsigned short*)(ws + 33554432);
  unsigned short* Wob = (unsigned short*)(ws + 35127296);
  float* Kp   = (float*)(ws + 35389440);
  float* Qp   = (float*)(ws + 68943872);
  float* AVBf = (float*)(ws + 102498304);
  unsigned short* ctx2 = (unsigned short*)(ws + 236716032);
  float* ctx  = out;                 // fp32 scratch, overwritten by out_gemm
  float* gate = out + 8388608;       // fp32 scratch, overwritten by out_gemm
  float* Sfin = out + 16777216;      // final state output

  cvt_f32_bf16<<<2048, 256, 0, stream>>>(hidden, hb, M_TOK * HID / 4);
  cvt_f32_bf16<<<64, 256, 0, stream>>>(W_k,     Wc + 0 * 131072, 32768);
  cvt_f32_bf16<<<64, 256, 0, stream>>>(W_v,     Wc + 1 * 131072, 32768);
  cvt_f32_bf16<<<64, 256, 0, stream>>>(W_q,     Wc + 2 * 131072, 32768);
  cvt_f32_bf16<<<64, 256, 0, stream>>>(W_beta,  Wc + 3 * 131072, 32768);
  cvt_f32_bf16<<<64, 256, 0, stream>>>(W_alpha, Wc + 4 * 131072, 32768);
  cvt_f32_bf16<<<64, 256, 0, stream>>>(gate_W,  Wc + 5 * 131072, 32768);
  cvt_f32_bf16<<<64, 256, 0, stream>>>(W_out,   Wob, 32768);

  proj_gemm<<<dim3(256, 24), 256, 0, stream>>>(hb, Wc, b_beta, b_alpha, Kp, Qp, AVBf, gate);
  knorm<<<32768, 256, 0, stream>>>(Kp);
  scan_kernel<<<128, 64, 0, stream>>>(Kp, Qp, (const float4*)AVBf, state, ctx, Sfin);
  rms_silu<<<8192, 256, 0, stream>>>(ctx, gate, norm_w, ctx2);
  out_gemm<<<dim3(256, 8), 256, 0, stream>>>(ctx2, Wob, out);
}